// Round 12
// baseline (784.390 us; speedup 1.0000x reference)
//
#include <hip/hip_runtime.h>
#include <utility>

// SPDConv2D: recursive weighted geometric mean of 8x8 SPD matrices.
// One wave per (o,site) chain; lane l holds element (i,j)=(l>>3,l&7).
// R11: dual-chain {Y, Linv} forward substitution (independent, interleaved)
//      + one-level congruence Z = Linv*Y^T (solve section 18 -> 10 serial
//      DS levels); no explicit symmetrize; epilogue eigenweights from the
//      replicated diag D (no readlane chain); sweep cap 4.

static __device__ __forceinline__ float bper(int byteidx, float v) {
  return __int_as_float(__builtin_amdgcn_ds_bpermute(byteidx, __float_as_int(v)));
}
static __device__ __forceinline__ float rl(float v, int lane_u) {
  return __int_as_float(__builtin_amdgcn_readlane(__float_as_int(v), lane_u));
}
template <int P>
static __device__ __forceinline__ float swz(float v) {
  return __int_as_float(__builtin_amdgcn_ds_swizzle(__float_as_int(v), P));
}
static __device__ __forceinline__ float dpp_ror8(float v) {
  // within each 16-lane row, rotate by 8 == lane^8
  return __int_as_float(__builtin_amdgcn_update_dpp(0, __float_as_int(v), 0x128, 0xF, 0xF, true));
}
static __device__ __forceinline__ float rcpf_(float x) { return __builtin_amdgcn_rcpf(x); }
static __device__ __forceinline__ float rsqf_(float x) { return __builtin_amdgcn_rsqf(x); }

// Broadcast octet position R (0..7) to all 8 lanes of each octet (DPP only).
template <int R>
static __device__ __forceinline__ float obcast(float v, bool hi) {
  const int x = __float_as_int(v);
  const int a = __builtin_amdgcn_update_dpp(0, x, (R & 3) * 0x55, 0xF, 0xF, false);
  const int m = __builtin_amdgcn_update_dpp(0, a, 0x141, 0xF, 0xF, false);
  const int r = (R < 4) ? (hi ? m : a) : (hi ? a : m);
  return __int_as_float(r);
}

template <class F, int... Is>
static __device__ __forceinline__ void sfor_impl(F&& f, std::integer_sequence<int, Is...>) {
  (f(std::integral_constant<int, Is>{}), ...);
}
template <int N, class F>
static __device__ __forceinline__ void sfor(F&& f) {
  sfor_impl(static_cast<F&&>(f), std::make_integer_sequence<int, N>{});
}

__global__ __launch_bounds__(64) void spd_fm_kernel(
    const float* __restrict__ x,      // (4,8,20,20,8,8) f32
    const float* __restrict__ wm,     // (16,72) f32
    float* __restrict__ out)          // (4,16,9,9,8,8) f32
{
  const int wid = blockIdx.x;
  const int lane = threadIdx.x;
  const int i = lane >> 3, j = lane & 7;
  const bool hi = (lane & 4) != 0;

  const int o    = wid / 324;
  const int site = wid - o * 324;
  const int b   = site / 81;
  const int r81 = site - b * 81;
  const int ho  = r81 / 9;
  const int wo  = r81 - ho * 9;

  const float* xb   = x + b * 204800 + (ho * 2) * 1280 + (wo * 2) * 64 + lane;
  const float* wrow = wm + o * 72;

  const int tp      = (((j << 3) | i)) << 2;  // transpose byte-index
  const int jj5     = j << 5;                 // byte base for src=(j<<3)|kk
  const int j2      = j << 2;                 // byte base for src=(r<<3)|j
  const int bx_ii   = (i * 9) << 2;           // lane (i,i)
  const int bx_self = lane << 2;              // own lane

  // t[o,k] = w^2/cumsum(w^2) (eps cancels); t0 == 1 => M = sym(X_0)
  float w0 = wrow[0];
  float csum = w0 * w0;
  float M = xb[0];
  M = 0.5f * (M + bper(tp, M));

  float Xc = xb[25600];  // k=1: kh=0,kw=0,c=1
  for (int k = 1; k < 72; ++k) {
    // prefetch X for k+1
    float Xn = 0.0f;
    if (k + 1 < 72) {
      const int k1 = k + 1;
      const int kh = k1 / 24;
      const int rr = k1 - kh * 24;
      Xn = xb[(rr & 7) * 25600 + kh * 1280 + (rr >> 3) * 64];
    }

    float wv = wrow[k];
    wv *= wv;
    csum += wv;
    const float tk = wv * rcpf_(csum);

    // ---- Cholesky M = L L^T ----
    float a = M;
    float dinv = 0.0f;  // diag lanes hold 1/L_kk
    sfor<8>([&](auto KK) {
      constexpr int kk = KK.value;
      const float akk  = fmaxf(rl(a, 9 * kk), 1e-20f);
      const float rinv = rsqf_(akk);
      if (j == kk) a = (i == kk) ? akk * rinv : a * rinv;
      if (i == kk && j == kk) dinv = rinv;
      const float lik = obcast<kk>(a, hi);          // L[i][kk] via DPP
      const float ljk = bper(jj5 | (kk << 2), a);   // L[j][kk]
      if (i > kk && j > kk) a = fmaf(-lik, ljk, a);
    });
    const float Lm = (j <= i) ? a : 0.0f;

    // prefetch L[i][r]: immediate swizzles (and=0x18 keeps i-bits, or=r)
    float lir[8];
    sfor<8>([&](auto RR) {
      constexpr int r = RR.value;
      lir[r] = swz<(r << 5) | 0x18>(Lm);
    });

    // ---- dual-chain forward substitution: Y = L^{-1} X  and  Linv = L^{-1} I
    //      (independent chains, interleaved for ILP) ----
    float y = Xc;
    float v = (i == j) ? 1.0f : 0.0f;
    sfor<8>([&](auto RR) {
      constexpr int r = RR.value;
      const float dr = rl(dinv, 9 * r);
      if (i == r) { y *= dr; v *= dr; }
      const float yr = bper((r << 5) | j2, y);      // Y[r][j]
      const float vr = bper((r << 5) | j2, v);      // Linv[r][j]
      if (i > r) {
        y = fmaf(-lir[r], yr, y);
        v = fmaf(-lir[r], vr, v);
      }
    });

    // ---- Z = Linv * Y^T  (one parallel-fetch matmul level; symmetric
    //      to fp rounding, no explicit symmetrize needed) ----
    float z = 0.0f;
    sfor<8>([&](auto KK) {
      constexpr int kk = KK.value;
      const float lik = swz<(kk << 5) | 0x18>(v);   // Linv[i][kk]
      const float yjk = bper(jj5 | (kk << 2), y);   // Y[j][kk]
      z = fmaf(lik, yjk, z);
    });

    // ---- replicated diag D; trace via xor-tree on D (invariant) ----
    float D = bper(bx_ii, z);               // Z[i][i], replicated along row
    float t8 = D + dpp_ror8(D);             // + i^1
    t8 += swz<0x401F>(t8);                  // + i^2
    const float trz = t8 + bper(bx_self ^ 128, t8);  // + i^4
    const float s2 = 1.0e-6f * trz * trz;

    // ---- XOR-paired Jacobi (transpose trick), W = (L*prodJ)^T ----
    float W = bper(tp, Lm);
    auto jacobi_sweep = [&]() {
      sfor<7>([&](auto RR) {
        constexpr int r   = RR.value + 1;
        constexpr int xc  = r << 2;         // col-field xor on byte addr
        constexpr int xr  = r << 5;         // row-field xor on byte addr
        constexpr int msb = (r >= 4) ? 4 : ((r >= 2) ? 2 : 1);  // pair order bit
        float zr, Dq, Wr;
        if constexpr (r < 4) {
          constexpr int P = ((r << 3) << 10) | 0x1F;  // lane ^ (r<<3), in-half
          zr = swz<P>(z);
          Dq = swz<P>(D);
          Wr = swz<P>(W);
        } else {
          zr = bper(bx_self ^ xr, z);
          Dq = bper(bx_self ^ xr, D);
          Wr = bper(bx_self ^ xr, W);
        }
        const float aR = bper(bx_ii ^ xc, z);     // Z[i][i^r]
        // rotation for pair {i, i^r}; antisymmetric sign, tie-break by order
        const float dd = D - Dq;
        const float q2 = aR + aR;
        const float h2 = fmaf(dd, dd, q2 * q2);
        const float rh = rsqf_(fmaxf(h2, 1e-38f));
        const float c2 = fmaf(0.5f * fabsf(dd), rh, 0.5f);
        const float rc = rsqf_(c2);
        const bool ok  = h2 > 1e-38f;
        const float cc = ok ? c2 * rc : 1.0f;
        const float tt = aR * (rh * rc);
        const bool neg = (dd < 0.0f) || ((dd == 0.0f) && ((i & msb) != 0));
        float sR = neg ? -tt : tt;
        sR = ok ? sR : 0.0f;
        // row op: G = J^T Z ; W' = J^T W ; local diag update (exact)
        const float G = fmaf(sR, zr, cc * z);
        W = fmaf(sR, Wr, cc * W);
        D = fmaf(cc, fmaf(cc, D, sR * aR), sR * fmaf(cc, aR, sR * Dq));
        // second level: z' = J^T G^T (two independent fetches from G)
        const float T  = bper(tp, G);        // G[j][i]
        const float T2 = bper(tp ^ xc, G);   // G[j][i^r]
        z = fmaf(sR, T2, cc * T);
      });
    };
    jacobi_sweep();
    jacobi_sweep();
#pragma unroll 1
    for (int s = 2; s < 4; ++s) {
      const bool off = (i < j) && (z * z > s2);
      if (__ballot(off) == 0ull) break;
      jacobi_sweep();
    }

    // ---- eigenweights from D (all lanes): ev_i^tk, transpose -> ev_j^tk ----
    const float wdl = __builtin_amdgcn_exp2f(tk * __builtin_amdgcn_logf(fmaxf(D, 1e-10f)));
    const float wdT = bper(tp, wdl);         // lane (i,j): ev_j^tk

    // ---- U = W^T ; Mn = U diag(ev^tk) U^T ----
    const float U   = bper(tp, W);
    const float Usc = U * wdT;               // U[i][j] * ev_j^tk
    float mn = 0.0f;
    sfor<8>([&](auto KK) {
      constexpr int kk = KK.value;
      const float a1 = swz<(kk << 5) | 0x18>(Usc);  // U[i][kk]*ev_kk^tk
      const float a2 = bper(jj5 | (kk << 2), U);    // U[j][kk]
      mn = fmaf(a1, a2, mn);
    });
    M = 0.5f * (mn + bper(tp, mn));
    Xc = Xn;
  }

  out[(size_t)((b * 16 + o) * 81 + r81) * 64 + lane] = M;
}

extern "C" void kernel_launch(void* const* d_in, const int* in_sizes, int n_in,
                              void* d_out, int out_size, void* d_ws, size_t ws_size,
                              hipStream_t stream) {
  const float* x  = (const float*)d_in[0];
  const float* wm = (const float*)d_in[1];
  float* out = (float*)d_out;
  // 5184 chains, 1 wave each, 1 wave per block
  spd_fm_kernel<<<5184, 64, 0, stream>>>(x, wm, out);
}

// Round 13
// 753.983 us; speedup vs baseline: 1.0403x; 1.0403x over previous
//
#include <hip/hip_runtime.h>
#include <utility>

// SPDConv2D: recursive weighted geometric mean of 8x8 SPD matrices.
// One wave per (o,site) chain; lane l holds element (i,j)=(l>>3,l&7).
// R12: R10 base (best: 770us) + unit-lower solves (L = Lunit*Dhat; no
//      readlane/mul inside solve levels) + R11's all-lane eigenweight
//      epilogue + no explicit symmetrize + sweep cap 4.

static __device__ __forceinline__ float bper(int byteidx, float v) {
  return __int_as_float(__builtin_amdgcn_ds_bpermute(byteidx, __float_as_int(v)));
}
static __device__ __forceinline__ float rl(float v, int lane_u) {
  return __int_as_float(__builtin_amdgcn_readlane(__float_as_int(v), lane_u));
}
template <int P>
static __device__ __forceinline__ float swz(float v) {
  return __int_as_float(__builtin_amdgcn_ds_swizzle(__float_as_int(v), P));
}
static __device__ __forceinline__ float dpp_ror8(float v) {
  // within each 16-lane row, rotate by 8 == lane^8
  return __int_as_float(__builtin_amdgcn_update_dpp(0, __float_as_int(v), 0x128, 0xF, 0xF, true));
}
static __device__ __forceinline__ float rcpf_(float x) { return __builtin_amdgcn_rcpf(x); }
static __device__ __forceinline__ float rsqf_(float x) { return __builtin_amdgcn_rsqf(x); }

// Broadcast octet position R (0..7) to all 8 lanes of each octet (DPP only).
template <int R>
static __device__ __forceinline__ float obcast(float v, bool hi) {
  const int x = __float_as_int(v);
  const int a = __builtin_amdgcn_update_dpp(0, x, (R & 3) * 0x55, 0xF, 0xF, false);
  const int m = __builtin_amdgcn_update_dpp(0, a, 0x141, 0xF, 0xF, false);
  const int r = (R < 4) ? (hi ? m : a) : (hi ? a : m);
  return __int_as_float(r);
}

template <class F, int... Is>
static __device__ __forceinline__ void sfor_impl(F&& f, std::integer_sequence<int, Is...>) {
  (f(std::integral_constant<int, Is>{}), ...);
}
template <int N, class F>
static __device__ __forceinline__ void sfor(F&& f) {
  sfor_impl(static_cast<F&&>(f), std::make_integer_sequence<int, N>{});
}

__global__ __launch_bounds__(64) void spd_fm_kernel(
    const float* __restrict__ x,      // (4,8,20,20,8,8) f32
    const float* __restrict__ wm,     // (16,72) f32
    float* __restrict__ out)          // (4,16,9,9,8,8) f32
{
  const int wid = blockIdx.x;
  const int lane = threadIdx.x;
  const int i = lane >> 3, j = lane & 7;
  const bool hi = (lane & 4) != 0;

  const int o    = wid / 324;
  const int site = wid - o * 324;
  const int b   = site / 81;
  const int r81 = site - b * 81;
  const int ho  = r81 / 9;
  const int wo  = r81 - ho * 9;

  const float* xb   = x + b * 204800 + (ho * 2) * 1280 + (wo * 2) * 64 + lane;
  const float* wrow = wm + o * 72;

  const int tp      = (((j << 3) | i)) << 2;  // transpose byte-index
  const int jj5     = j << 5;                 // byte base for src=(j<<3)|kk
  const int j2      = j << 2;                 // byte base for src=(r<<3)|j
  const int bx_ii   = (i * 9) << 2;           // lane (i,i)
  const int bx_self = lane << 2;              // own lane

  // t[o,k] = w^2/cumsum(w^2) (eps cancels); t0 == 1 => M = sym(X_0)
  float w0 = wrow[0];
  float csum = w0 * w0;
  float M = xb[0];
  M = 0.5f * (M + bper(tp, M));

  float Xc = xb[25600];  // k=1: kh=0,kw=0,c=1
  for (int k = 1; k < 72; ++k) {
    // prefetch X for k+1
    float Xn = 0.0f;
    if (k + 1 < 72) {
      const int k1 = k + 1;
      const int kh = k1 / 24;
      const int rr = k1 - kh * 24;
      Xn = xb[(rr & 7) * 25600 + kh * 1280 + (rr >> 3) * 64];
    }

    float wv = wrow[k];
    wv *= wv;
    csum += wv;
    const float tk = wv * rcpf_(csum);

    // ---- Cholesky M = L L^T ----
    float a = M;
    float dinv = 0.0f;  // diag lanes hold 1/L_kk
    sfor<8>([&](auto KK) {
      constexpr int kk = KK.value;
      const float akk  = fmaxf(rl(a, 9 * kk), 1e-20f);
      const float rinv = rsqf_(akk);
      if (j == kk) a = (i == kk) ? akk * rinv : a * rinv;
      if (i == kk && j == kk) dinv = rinv;
      const float lik = obcast<kk>(a, hi);          // L[i][kk] via DPP
      const float ljk = bper(jj5 | (kk << 2), a);   // L[j][kk]
      if (i > kk && j > kk) a = fmaf(-lik, ljk, a);
    });
    const float Lm = (j <= i) ? a : 0.0f;

    // ---- unit-lower factor: Lu = Lm * diag(dinv) (column scaled) ----
    const float dv  = bper(bx_ii, dinv);   // lane (i,j): 1/L_ii (row-replicated)
    const float dvC = bper(tp, dv);        // lane (i,j): 1/L_jj (col-replicated)
    const float Lu  = Lm * dvC;            // Lu[i][r] = L[i][r]/L_rr, diag ~1

    // prefetch Lu[i][r]: immediate swizzles (and=0x18 keeps i-bits, or=r)
    float lir[8];
    sfor<8>([&](auto RR) {
      constexpr int r = RR.value;
      lir[r] = swz<(r << 5) | 0x18>(Lu);
    });

    // ---- Y = L^{-1} X: unit forward solve, then row scale ----
    float y = Xc;
    sfor<8>([&](auto RR) {
      constexpr int r = RR.value;
      const float yr = bper((r << 5) | j2, y);      // W[r][j] (serial chain)
      if (i > r) y = fmaf(-lir[r], yr, y);
    });
    y *= dv;

    // ---- Z = L^{-1} Y^T: unit forward solve, then row scale ----
    float z = bper(tp, y);
    sfor<8>([&](auto RR) {
      constexpr int r = RR.value;
      const float zr = bper((r << 5) | j2, z);
      if (i > r) z = fmaf(-lir[r], zr, z);
    });
    z *= dv;

    // ---- replicated diag D; trace via xor-tree on D (invariant) ----
    float D = bper(bx_ii, z);               // Z[i][i], replicated along row
    float t8 = D + dpp_ror8(D);             // + i^1
    t8 += swz<0x401F>(t8);                  // + i^2
    const float trz = t8 + bper(bx_self ^ 128, t8);  // + i^4
    const float s2 = 1.0e-6f * trz * trz;

    // ---- XOR-paired Jacobi (transpose trick), W = (L*prodJ)^T ----
    float W = bper(tp, Lm);
    auto jacobi_sweep = [&]() {
      sfor<7>([&](auto RR) {
        constexpr int r   = RR.value + 1;
        constexpr int xc  = r << 2;         // col-field xor on byte addr
        constexpr int xr  = r << 5;         // row-field xor on byte addr
        constexpr int msb = (r >= 4) ? 4 : ((r >= 2) ? 2 : 1);  // pair order bit
        float zr, Dq, Wr;
        if constexpr (r < 4) {
          constexpr int P = ((r << 3) << 10) | 0x1F;  // lane ^ (r<<3), in-half
          zr = swz<P>(z);
          Dq = swz<P>(D);
          Wr = swz<P>(W);
        } else {
          zr = bper(bx_self ^ xr, z);
          Dq = bper(bx_self ^ xr, D);
          Wr = bper(bx_self ^ xr, W);
        }
        const float aR = bper(bx_ii ^ xc, z);     // Z[i][i^r]
        // rotation for pair {i, i^r}; antisymmetric sign, tie-break by order
        const float dd = D - Dq;
        const float q2 = aR + aR;
        const float h2 = fmaf(dd, dd, q2 * q2);
        const float rh = rsqf_(fmaxf(h2, 1e-38f));
        const float c2 = fmaf(0.5f * fabsf(dd), rh, 0.5f);
        const float rc = rsqf_(c2);
        const bool ok  = h2 > 1e-38f;
        const float cc = ok ? c2 * rc : 1.0f;
        const float tt = aR * (rh * rc);
        const bool neg = (dd < 0.0f) || ((dd == 0.0f) && ((i & msb) != 0));
        float sR = neg ? -tt : tt;
        sR = ok ? sR : 0.0f;
        // row op: G = J^T Z ; W' = J^T W ; local diag update (exact)
        const float G = fmaf(sR, zr, cc * z);
        W = fmaf(sR, Wr, cc * W);
        D = fmaf(cc, fmaf(cc, D, sR * aR), sR * fmaf(cc, aR, sR * Dq));
        // second level: z' = J^T G^T (two independent fetches from G)
        const float T  = bper(tp, G);        // G[j][i]
        const float T2 = bper(tp ^ xc, G);   // G[j][i^r]
        z = fmaf(sR, T2, cc * T);
      });
    };
    jacobi_sweep();
    jacobi_sweep();
#pragma unroll 1
    for (int s = 2; s < 4; ++s) {
      const bool off = (i < j) && (z * z > s2);
      if (__ballot(off) == 0ull) break;
      jacobi_sweep();
    }

    // ---- eigenweights from D (all lanes): ev_i^tk, transpose -> ev_j^tk ----
    const float wdl = __builtin_amdgcn_exp2f(tk * __builtin_amdgcn_logf(fmaxf(D, 1e-10f)));
    const float wdT = bper(tp, wdl);         // lane (i,j): ev_j^tk

    // ---- U = W^T ; Mn = U diag(ev^tk) U^T ----
    const float U   = bper(tp, W);
    const float Usc = U * wdT;               // U[i][j] * ev_j^tk
    float mn = 0.0f;
    sfor<8>([&](auto KK) {
      constexpr int kk = KK.value;
      const float a1 = swz<(kk << 5) | 0x18>(Usc);  // U[i][kk]*ev_kk^tk
      const float a2 = bper(jj5 | (kk << 2), U);    // U[j][kk]
      mn = fmaf(a1, a2, mn);
    });
    M = 0.5f * (mn + bper(tp, mn));
    Xc = Xn;
  }

  out[(size_t)((b * 16 + o) * 81 + r81) * 64 + lane] = M;
}

extern "C" void kernel_launch(void* const* d_in, const int* in_sizes, int n_in,
                              void* d_out, int out_size, void* d_ws, size_t ws_size,
                              hipStream_t stream) {
  const float* x  = (const float*)d_in[0];
  const float* wm = (const float*)d_in[1];
  float* out = (float*)d_out;
  // 5184 chains, 1 wave each, 1 wave per block
  spd_fm_kernel<<<5184, 64, 0, stream>>>(x, wm, out);
}

// Round 14
// 749.024 us; speedup vs baseline: 1.0472x; 1.0066x over previous
//
#include <hip/hip_runtime.h>
#include <utility>

// SPDConv2D: recursive weighted geometric mean of 8x8 SPD matrices.
// One wave per (o,site) chain; lane l holds element (i,j)=(l>>3,l&7).
// R13: 128-thr blocks (CDNA 16-WG/CU cap made 64-thr blocks tail-bound:
//      5184 1-wave WGs -> 1.27 rounds; 2592 2-wave WGs -> 1 round),
//      Jacobi r=1 via DPP row_ror:8 (VALU, not DS), epilogue directly
//      from W (no U transpose): mn = sum_k W[k][i]*(W[k][j]*wd_k).

static __device__ __forceinline__ float bper(int byteidx, float v) {
  return __int_as_float(__builtin_amdgcn_ds_bpermute(byteidx, __float_as_int(v)));
}
static __device__ __forceinline__ float rl(float v, int lane_u) {
  return __int_as_float(__builtin_amdgcn_readlane(__float_as_int(v), lane_u));
}
template <int P>
static __device__ __forceinline__ float swz(float v) {
  return __int_as_float(__builtin_amdgcn_ds_swizzle(__float_as_int(v), P));
}
static __device__ __forceinline__ float dpp_ror8(float v) {
  // within each 16-lane row, rotate by 8 == lane^8
  return __int_as_float(__builtin_amdgcn_update_dpp(0, __float_as_int(v), 0x128, 0xF, 0xF, true));
}
static __device__ __forceinline__ float rcpf_(float x) { return __builtin_amdgcn_rcpf(x); }
static __device__ __forceinline__ float rsqf_(float x) { return __builtin_amdgcn_rsqf(x); }

// Broadcast octet position R (0..7) to all 8 lanes of each octet (DPP only).
template <int R>
static __device__ __forceinline__ float obcast(float v, bool hi) {
  const int x = __float_as_int(v);
  const int a = __builtin_amdgcn_update_dpp(0, x, (R & 3) * 0x55, 0xF, 0xF, false);
  const int m = __builtin_amdgcn_update_dpp(0, a, 0x141, 0xF, 0xF, false);
  const int r = (R < 4) ? (hi ? m : a) : (hi ? a : m);
  return __int_as_float(r);
}

template <class F, int... Is>
static __device__ __forceinline__ void sfor_impl(F&& f, std::integer_sequence<int, Is...>) {
  (f(std::integral_constant<int, Is>{}), ...);
}
template <int N, class F>
static __device__ __forceinline__ void sfor(F&& f) {
  sfor_impl(static_cast<F&&>(f), std::make_integer_sequence<int, N>{});
}

__global__ __launch_bounds__(128) void spd_fm_kernel(
    const float* __restrict__ x,      // (4,8,20,20,8,8) f32
    const float* __restrict__ wm,     // (16,72) f32
    float* __restrict__ out)          // (4,16,9,9,8,8) f32
{
  const int wid = blockIdx.x * 2 + (threadIdx.x >> 6);
  if (wid >= 16 * 324) return;
  const int lane = threadIdx.x & 63;
  const int i = lane >> 3, j = lane & 7;
  const bool hi = (lane & 4) != 0;

  const int o    = wid / 324;
  const int site = wid - o * 324;
  const int b   = site / 81;
  const int r81 = site - b * 81;
  const int ho  = r81 / 9;
  const int wo  = r81 - ho * 9;

  const float* xb   = x + b * 204800 + (ho * 2) * 1280 + (wo * 2) * 64 + lane;
  const float* wrow = wm + o * 72;

  const int tp      = (((j << 3) | i)) << 2;  // transpose byte-index
  const int jj5     = j << 5;                 // byte base for src=(j<<3)|kk
  const int j2      = j << 2;                 // byte base for src=(r<<3)|j
  const int i2      = i << 2;                 // byte base for src=(k<<3)|i
  const int bx_ii   = (i * 9) << 2;           // lane (i,i)
  const int bx_self = lane << 2;              // own lane

  // t[o,k] = w^2/cumsum(w^2) (eps cancels); t0 == 1 => M = sym(X_0)
  float w0 = wrow[0];
  float csum = w0 * w0;
  float M = xb[0];
  M = 0.5f * (M + bper(tp, M));

  float Xc = xb[25600];  // k=1: kh=0,kw=0,c=1
  for (int k = 1; k < 72; ++k) {
    // prefetch X for k+1
    float Xn = 0.0f;
    if (k + 1 < 72) {
      const int k1 = k + 1;
      const int kh = k1 / 24;
      const int rr = k1 - kh * 24;
      Xn = xb[(rr & 7) * 25600 + kh * 1280 + (rr >> 3) * 64];
    }

    float wv = wrow[k];
    wv *= wv;
    csum += wv;
    const float tk = wv * rcpf_(csum);

    // ---- Cholesky M = L L^T ----
    float a = M;
    float dinv = 0.0f;  // diag lanes hold 1/L_kk
    sfor<8>([&](auto KK) {
      constexpr int kk = KK.value;
      const float akk  = fmaxf(rl(a, 9 * kk), 1e-20f);
      const float rinv = rsqf_(akk);
      if (j == kk) a = (i == kk) ? akk * rinv : a * rinv;
      if (i == kk && j == kk) dinv = rinv;
      const float lik = obcast<kk>(a, hi);          // L[i][kk] via DPP
      const float ljk = bper(jj5 | (kk << 2), a);   // L[j][kk]
      if (i > kk && j > kk) a = fmaf(-lik, ljk, a);
    });
    const float Lm = (j <= i) ? a : 0.0f;

    // ---- unit-lower factor: Lu = Lm * diag(dinv) (column scaled) ----
    const float dv  = bper(bx_ii, dinv);   // lane (i,j): 1/L_ii (row-replicated)
    const float dvC = bper(tp, dv);        // lane (i,j): 1/L_jj (col-replicated)
    const float Lu  = Lm * dvC;            // Lu[i][r] = L[i][r]/L_rr, diag ~1

    // prefetch Lu[i][r]: immediate swizzles (and=0x18 keeps i-bits, or=r)
    float lir[8];
    sfor<8>([&](auto RR) {
      constexpr int r = RR.value;
      lir[r] = swz<(r << 5) | 0x18>(Lu);
    });

    // ---- Y = L^{-1} X: unit forward solve, then row scale ----
    float y = Xc;
    sfor<8>([&](auto RR) {
      constexpr int r = RR.value;
      const float yr = bper((r << 5) | j2, y);      // serial chain
      if (i > r) y = fmaf(-lir[r], yr, y);
    });
    y *= dv;

    // ---- Z = L^{-1} Y^T: unit forward solve, then row scale ----
    float z = bper(tp, y);
    sfor<8>([&](auto RR) {
      constexpr int r = RR.value;
      const float zr = bper((r << 5) | j2, z);
      if (i > r) z = fmaf(-lir[r], zr, z);
    });
    z *= dv;

    // ---- replicated diag D; trace via xor-tree on D (invariant) ----
    float D = bper(bx_ii, z);               // Z[i][i], replicated along row
    float t8 = D + dpp_ror8(D);             // + i^1
    t8 += swz<0x401F>(t8);                  // + i^2
    const float trz = t8 + bper(bx_self ^ 128, t8);  // + i^4
    const float s2 = 1.0e-6f * trz * trz;

    // ---- XOR-paired Jacobi (transpose trick), W = (L*prodJ)^T ----
    float W = bper(tp, Lm);
    auto jacobi_sweep = [&]() {
      sfor<7>([&](auto RR) {
        constexpr int r   = RR.value + 1;
        constexpr int xc  = r << 2;         // col-field xor on byte addr
        constexpr int xr  = r << 5;         // row-field xor on byte addr
        constexpr int msb = (r >= 4) ? 4 : ((r >= 2) ? 2 : 1);  // pair order bit
        float zr, Dq, Wr;
        if constexpr (r == 1) {
          zr = dpp_ror8(z);                 // lane^8 via DPP (VALU, no DS)
          Dq = dpp_ror8(D);
          Wr = dpp_ror8(W);
        } else if constexpr (r < 4) {
          constexpr int P = ((r << 3) << 10) | 0x1F;  // lane ^ (r<<3), in-half
          zr = swz<P>(z);
          Dq = swz<P>(D);
          Wr = swz<P>(W);
        } else {
          zr = bper(bx_self ^ xr, z);
          Dq = bper(bx_self ^ xr, D);
          Wr = bper(bx_self ^ xr, W);
        }
        const float aR = bper(bx_ii ^ xc, z);     // Z[i][i^r]
        // rotation for pair {i, i^r}; antisymmetric sign, tie-break by order
        const float dd = D - Dq;
        const float q2 = aR + aR;
        const float h2 = fmaf(dd, dd, q2 * q2);
        const float rh = rsqf_(fmaxf(h2, 1e-38f));
        const float c2 = fmaf(0.5f * fabsf(dd), rh, 0.5f);
        const float rc = rsqf_(c2);
        const bool ok  = h2 > 1e-38f;
        const float cc = ok ? c2 * rc : 1.0f;
        const float tt = aR * (rh * rc);
        const bool neg = (dd < 0.0f) || ((dd == 0.0f) && ((i & msb) != 0));
        float sR = neg ? -tt : tt;
        sR = ok ? sR : 0.0f;
        // row op: G = J^T Z ; W' = J^T W ; local diag update (exact)
        const float G = fmaf(sR, zr, cc * z);
        W = fmaf(sR, Wr, cc * W);
        D = fmaf(cc, fmaf(cc, D, sR * aR), sR * fmaf(cc, aR, sR * Dq));
        // second level: z' = J^T G^T (two independent fetches from G)
        const float T  = bper(tp, G);        // G[j][i]
        const float T2 = bper(tp ^ xc, G);   // G[j][i^r]
        z = fmaf(sR, T2, cc * T);
      });
    };
    jacobi_sweep();
    jacobi_sweep();
#pragma unroll 1
    for (int s = 2; s < 4; ++s) {
      const bool off = (i < j) && (z * z > s2);
      if (__ballot(off) == 0ull) break;
      jacobi_sweep();
    }

    // ---- eigenweights from D (all lanes, row-indexed): ev_i^tk ----
    const float wdl = __builtin_amdgcn_exp2f(tk * __builtin_amdgcn_logf(fmaxf(D, 1e-10f)));
    const float Ws  = W * wdl;   // Ws[k][j] = W[k][j] * ev_k^tk (local mul)

    // ---- Mn[i][j] = sum_k W[k][i] * Ws[k][j] (U never materialized) ----
    float mn = 0.0f;
    sfor<8>([&](auto KK) {
      constexpr int kk = KK.value;
      const float a1 = bper((kk << 5) | i2, W);    // W[kk][i] = U[i][kk]
      const float a2 = bper((kk << 5) | j2, Ws);   // U[j][kk]*ev_kk^tk
      mn = fmaf(a1, a2, mn);
    });
    M = 0.5f * (mn + bper(tp, mn));
    Xc = Xn;
  }

  out[(size_t)((b * 16 + o) * 81 + r81) * 64 + lane] = M;
}

extern "C" void kernel_launch(void* const* d_in, const int* in_sizes, int n_in,
                              void* d_out, int out_size, void* d_ws, size_t ws_size,
                              hipStream_t stream) {
  const float* x  = (const float*)d_in[0];
  const float* wm = (const float*)d_in[1];
  float* out = (float*)d_out;
  // 5184 chains, 2 waves per 128-thr block -> 2592 blocks (<=16 WG/CU cap,
  // all waves co-resident in one dispatch round)
  spd_fm_kernel<<<2592, 128, 0, stream>>>(x, wm, out);
}

// Round 15
// 714.420 us; speedup vs baseline: 1.0979x; 1.0484x over previous
//
#include <hip/hip_runtime.h>
#include <utility>

// SPDConv2D: recursive weighted geometric mean of 8x8 SPD matrices.
// One wave per (o,site) chain; lane l holds element (i,j)=(l>>3,l&7).
// R14: unpredicated solves (zeroed-diag unit factor Lz), both symmetrizes
//      dropped (X exactly symmetric; Mn symmetric to 1 ulp and Cholesky
//      reads lower triangle only), sweep cap 3 (2 fixed + <=1 conditional).

static __device__ __forceinline__ float bper(int byteidx, float v) {
  return __int_as_float(__builtin_amdgcn_ds_bpermute(byteidx, __float_as_int(v)));
}
static __device__ __forceinline__ float rl(float v, int lane_u) {
  return __int_as_float(__builtin_amdgcn_readlane(__float_as_int(v), lane_u));
}
template <int P>
static __device__ __forceinline__ float swz(float v) {
  return __int_as_float(__builtin_amdgcn_ds_swizzle(__float_as_int(v), P));
}
static __device__ __forceinline__ float dpp_ror8(float v) {
  // within each 16-lane row, rotate by 8 == lane^8
  return __int_as_float(__builtin_amdgcn_update_dpp(0, __float_as_int(v), 0x128, 0xF, 0xF, true));
}
static __device__ __forceinline__ float rcpf_(float x) { return __builtin_amdgcn_rcpf(x); }
static __device__ __forceinline__ float rsqf_(float x) { return __builtin_amdgcn_rsqf(x); }

// Broadcast octet position R (0..7) to all 8 lanes of each octet (DPP only).
template <int R>
static __device__ __forceinline__ float obcast(float v, bool hi) {
  const int x = __float_as_int(v);
  const int a = __builtin_amdgcn_update_dpp(0, x, (R & 3) * 0x55, 0xF, 0xF, false);
  const int m = __builtin_amdgcn_update_dpp(0, a, 0x141, 0xF, 0xF, false);
  const int r = (R < 4) ? (hi ? m : a) : (hi ? a : m);
  return __int_as_float(r);
}

template <class F, int... Is>
static __device__ __forceinline__ void sfor_impl(F&& f, std::integer_sequence<int, Is...>) {
  (f(std::integral_constant<int, Is>{}), ...);
}
template <int N, class F>
static __device__ __forceinline__ void sfor(F&& f) {
  sfor_impl(static_cast<F&&>(f), std::make_integer_sequence<int, N>{});
}

__global__ __launch_bounds__(128) void spd_fm_kernel(
    const float* __restrict__ x,      // (4,8,20,20,8,8) f32
    const float* __restrict__ wm,     // (16,72) f32
    float* __restrict__ out)          // (4,16,9,9,8,8) f32
{
  const int wid = blockIdx.x * 2 + (threadIdx.x >> 6);
  if (wid >= 16 * 324) return;
  const int lane = threadIdx.x & 63;
  const int i = lane >> 3, j = lane & 7;
  const bool hi = (lane & 4) != 0;

  const int o    = wid / 324;
  const int site = wid - o * 324;
  const int b   = site / 81;
  const int r81 = site - b * 81;
  const int ho  = r81 / 9;
  const int wo  = r81 - ho * 9;

  const float* xb   = x + b * 204800 + (ho * 2) * 1280 + (wo * 2) * 64 + lane;
  const float* wrow = wm + o * 72;

  const int tp      = (((j << 3) | i)) << 2;  // transpose byte-index
  const int jj5     = j << 5;                 // byte base for src=(j<<3)|kk
  const int j2      = j << 2;                 // byte base for src=(r<<3)|j
  const int i2      = i << 2;                 // byte base for src=(k<<3)|i
  const int bx_ii   = (i * 9) << 2;           // lane (i,i)
  const int bx_self = lane << 2;              // own lane

  // t[o,k] = w^2/cumsum(w^2) (eps cancels); t0 == 1 => M = X_0
  // (X is EXACTLY symmetric in storage: A@A^T products commute, same order)
  float w0 = wrow[0];
  float csum = w0 * w0;
  float M = xb[0];

  float Xc = xb[25600];  // k=1: kh=0,kw=0,c=1
  for (int k = 1; k < 72; ++k) {
    // prefetch X for k+1
    float Xn = 0.0f;
    if (k + 1 < 72) {
      const int k1 = k + 1;
      const int kh = k1 / 24;
      const int rr = k1 - kh * 24;
      Xn = xb[(rr & 7) * 25600 + kh * 1280 + (rr >> 3) * 64];
    }

    float wv = wrow[k];
    wv *= wv;
    csum += wv;
    const float tk = wv * rcpf_(csum);

    // ---- Cholesky M = L L^T (reads lower triangle only) ----
    float a = M;
    float dinv = 0.0f;  // diag lanes hold 1/L_kk
    sfor<8>([&](auto KK) {
      constexpr int kk = KK.value;
      const float akk  = fmaxf(rl(a, 9 * kk), 1e-20f);
      const float rinv = rsqf_(akk);
      if (j == kk) a = (i == kk) ? akk * rinv : a * rinv;
      if (i == kk && j == kk) dinv = rinv;
      const float lik = obcast<kk>(a, hi);          // L[i][kk] via DPP
      const float ljk = bper(jj5 | (kk << 2), a);   // L[j][kk]
      if (i > kk && j > kk) a = fmaf(-lik, ljk, a);
    });
    const float Lm = (j <= i) ? a : 0.0f;

    // ---- strictly-lower unit factor: Lz[i][r] = L[i][r]/L_rr for r<i, else 0
    const float dv  = bper(bx_ii, dinv);   // lane (i,j): 1/L_ii (row-replicated)
    const float dvC = bper(tp, dv);        // lane (i,j): 1/L_jj (col-replicated)
    const float Lz  = (j < i) ? Lm * dvC : 0.0f;

    // prefetch Lz[i][r]: immediate swizzles (and=0x18 keeps i-bits, or=r)
    float lir[8];
    sfor<8>([&](auto RR) {
      constexpr int r = RR.value;
      lir[r] = swz<(r << 5) | 0x18>(Lz);
    });

    // ---- Y = L^{-1} X: unit forward solve (unpredicated), row scale ----
    float y = Xc;
    sfor<8>([&](auto RR) {
      constexpr int r = RR.value;
      const float yr = bper((r << 5) | j2, y);      // serial chain
      y = fmaf(-lir[r], yr, y);                     // lir==0 for i<=r
    });
    y *= dv;

    // ---- Z = L^{-1} Y^T: unit forward solve (unpredicated), row scale ----
    float z = bper(tp, y);
    sfor<8>([&](auto RR) {
      constexpr int r = RR.value;
      const float zr = bper((r << 5) | j2, z);
      z = fmaf(-lir[r], zr, z);
    });
    z *= dv;

    // ---- replicated diag D; trace via xor-tree on D (invariant) ----
    float D = bper(bx_ii, z);               // Z[i][i], replicated along row
    float t8 = D + dpp_ror8(D);             // + i^1
    t8 += swz<0x401F>(t8);                  // + i^2
    const float trz = t8 + bper(bx_self ^ 128, t8);  // + i^4
    const float s2 = 1.0e-6f * trz * trz;

    // ---- XOR-paired Jacobi (transpose trick), W = (L*prodJ)^T ----
    float W = bper(tp, Lm);
    auto jacobi_sweep = [&]() {
      sfor<7>([&](auto RR) {
        constexpr int r   = RR.value + 1;
        constexpr int xc  = r << 2;         // col-field xor on byte addr
        constexpr int xr  = r << 5;         // row-field xor on byte addr
        constexpr int msb = (r >= 4) ? 4 : ((r >= 2) ? 2 : 1);  // pair order bit
        float zr, Dq, Wr;
        if constexpr (r == 1) {
          zr = dpp_ror8(z);                 // lane^8 via DPP (VALU, no DS)
          Dq = dpp_ror8(D);
          Wr = dpp_ror8(W);
        } else if constexpr (r < 4) {
          constexpr int P = ((r << 3) << 10) | 0x1F;  // lane ^ (r<<3), in-half
          zr = swz<P>(z);
          Dq = swz<P>(D);
          Wr = swz<P>(W);
        } else {
          zr = bper(bx_self ^ xr, z);
          Dq = bper(bx_self ^ xr, D);
          Wr = bper(bx_self ^ xr, W);
        }
        const float aR = bper(bx_ii ^ xc, z);     // Z[i][i^r]
        // rotation for pair {i, i^r}; antisymmetric sign, tie-break by order
        const float dd = D - Dq;
        const float q2 = aR + aR;
        const float h2 = fmaf(dd, dd, q2 * q2);
        const float rh = rsqf_(fmaxf(h2, 1e-38f));
        const float c2 = fmaf(0.5f * fabsf(dd), rh, 0.5f);
        const float rc = rsqf_(c2);
        const bool ok  = h2 > 1e-38f;
        const float cc = ok ? c2 * rc : 1.0f;
        const float tt = aR * (rh * rc);
        const bool neg = (dd < 0.0f) || ((dd == 0.0f) && ((i & msb) != 0));
        float sR = neg ? -tt : tt;
        sR = ok ? sR : 0.0f;
        // row op: G = J^T Z ; W' = J^T W ; local diag update (exact)
        const float G = fmaf(sR, zr, cc * z);
        W = fmaf(sR, Wr, cc * W);
        D = fmaf(cc, fmaf(cc, D, sR * aR), sR * fmaf(cc, aR, sR * Dq));
        // second level: z' = J^T G^T (two independent fetches from G)
        const float T  = bper(tp, G);        // G[j][i]
        const float T2 = bper(tp ^ xc, G);   // G[j][i^r]
        z = fmaf(sR, T2, cc * T);
      });
    };
    jacobi_sweep();
    jacobi_sweep();
    {
      const bool off = (i < j) && (z * z > s2);
      if (__ballot(off) != 0ull) jacobi_sweep();
    }

    // ---- eigenweights from D (all lanes, row-indexed): ev_i^tk ----
    const float wdl = __builtin_amdgcn_exp2f(tk * __builtin_amdgcn_logf(fmaxf(D, 1e-10f)));
    const float Ws  = W * wdl;   // Ws[k][j] = W[k][j] * ev_k^tk (local mul)

    // ---- Mn[i][j] = sum_k W[k][i] * Ws[k][j]; symmetric to 1 ulp and
    //      Cholesky reads lower only -> no symmetrize needed ----
    float mn = 0.0f;
    sfor<8>([&](auto KK) {
      constexpr int kk = KK.value;
      const float a1 = bper((kk << 5) | i2, W);    // W[kk][i] = U[i][kk]
      const float a2 = bper((kk << 5) | j2, Ws);   // U[j][kk]*ev_kk^tk
      mn = fmaf(a1, a2, mn);
    });
    M = mn;
    Xc = Xn;
  }

  out[(size_t)((b * 16 + o) * 81 + r81) * 64 + lane] = M;
}

extern "C" void kernel_launch(void* const* d_in, const int* in_sizes, int n_in,
                              void* d_out, int out_size, void* d_ws, size_t ws_size,
                              hipStream_t stream) {
  const float* x  = (const float*)d_in[0];
  const float* wm = (const float*)d_in[1];
  float* out = (float*)d_out;
  // 5184 chains, 2 waves per 128-thr block -> 2592 blocks
  spd_fm_kernel<<<2592, 128, 0, stream>>>(x, wm, out);
}

// Round 17
// 699.250 us; speedup vs baseline: 1.1218x; 1.0217x over previous
//
#include <hip/hip_runtime.h>
#include <utility>

// SPDConv2D: recursive weighted geometric mean of 8x8 SPD matrices.
// One wave per (o,site) chain; lane l holds element (i,j)=(l>>3,l&7).
// R16: revert R15's sweep removal (2 sweeps under-converge: absmax 0.031 >
//      thr 0.029). Restore R14's conditional 3rd sweep (trace tree+ballot).
//      Keep the epsilon-bias sign tie-break (2 ops, antisymmetry verified).

static __device__ __forceinline__ float bper(int byteidx, float v) {
  return __int_as_float(__builtin_amdgcn_ds_bpermute(byteidx, __float_as_int(v)));
}
static __device__ __forceinline__ float rl(float v, int lane_u) {
  return __int_as_float(__builtin_amdgcn_readlane(__float_as_int(v), lane_u));
}
template <int P>
static __device__ __forceinline__ float swz(float v) {
  return __int_as_float(__builtin_amdgcn_ds_swizzle(__float_as_int(v), P));
}
static __device__ __forceinline__ float dpp_ror8(float v) {
  // within each 16-lane row, rotate by 8 == lane^8
  return __int_as_float(__builtin_amdgcn_update_dpp(0, __float_as_int(v), 0x128, 0xF, 0xF, true));
}
static __device__ __forceinline__ float rcpf_(float x) { return __builtin_amdgcn_rcpf(x); }
static __device__ __forceinline__ float rsqf_(float x) { return __builtin_amdgcn_rsqf(x); }

// Broadcast octet position R (0..7) to all 8 lanes of each octet (DPP only).
template <int R>
static __device__ __forceinline__ float obcast(float v, bool hi) {
  const int x = __float_as_int(v);
  const int a = __builtin_amdgcn_update_dpp(0, x, (R & 3) * 0x55, 0xF, 0xF, false);
  const int m = __builtin_amdgcn_update_dpp(0, a, 0x141, 0xF, 0xF, false);
  const int r = (R < 4) ? (hi ? m : a) : (hi ? a : m);
  return __int_as_float(r);
}

template <class F, int... Is>
static __device__ __forceinline__ void sfor_impl(F&& f, std::integer_sequence<int, Is...>) {
  (f(std::integral_constant<int, Is>{}), ...);
}
template <int N, class F>
static __device__ __forceinline__ void sfor(F&& f) {
  sfor_impl(static_cast<F&&>(f), std::make_integer_sequence<int, N>{});
}

__global__ __launch_bounds__(128) void spd_fm_kernel(
    const float* __restrict__ x,      // (4,8,20,20,8,8) f32
    const float* __restrict__ wm,     // (16,72) f32
    float* __restrict__ out)          // (4,16,9,9,8,8) f32
{
  const int wid = blockIdx.x * 2 + (threadIdx.x >> 6);
  if (wid >= 16 * 324) return;
  const int lane = threadIdx.x & 63;
  const int i = lane >> 3, j = lane & 7;
  const bool hi = (lane & 4) != 0;

  const int o    = wid / 324;
  const int site = wid - o * 324;
  const int b   = site / 81;
  const int r81 = site - b * 81;
  const int ho  = r81 / 9;
  const int wo  = r81 - ho * 9;

  const float* xb   = x + b * 204800 + (ho * 2) * 1280 + (wo * 2) * 64 + lane;
  const float* wrow = wm + o * 72;

  const int tp      = (((j << 3) | i)) << 2;  // transpose byte-index
  const int jj5     = j << 5;                 // byte base for src=(j<<3)|kk
  const int j2      = j << 2;                 // byte base for src=(r<<3)|j
  const int i2      = i << 2;                 // byte base for src=(k<<3)|i
  const int bx_ii   = (i * 9) << 2;           // lane (i,i)
  const int bx_self = lane << 2;              // own lane

  // t[o,k] = w^2/cumsum(w^2) (eps cancels); t0 == 1 => M = X_0
  float w0 = wrow[0];
  float csum = w0 * w0;
  float M = xb[0];

  float Xc = xb[25600];  // k=1: kh=0,kw=0,c=1
  for (int k = 1; k < 72; ++k) {
    // prefetch X for k+1
    float Xn = 0.0f;
    if (k + 1 < 72) {
      const int k1 = k + 1;
      const int kh = k1 / 24;
      const int rr = k1 - kh * 24;
      Xn = xb[(rr & 7) * 25600 + kh * 1280 + (rr >> 3) * 64];
    }

    float wv = wrow[k];
    wv *= wv;
    csum += wv;
    const float tk = wv * rcpf_(csum);

    // ---- Cholesky M = L L^T (reads lower triangle only) ----
    float a = M;
    float dinv = 0.0f;  // diag lanes hold 1/L_kk
    sfor<8>([&](auto KK) {
      constexpr int kk = KK.value;
      const float akk  = fmaxf(rl(a, 9 * kk), 1e-20f);
      const float rinv = rsqf_(akk);
      if (j == kk) a = (i == kk) ? akk * rinv : a * rinv;
      if (i == kk && j == kk) dinv = rinv;
      const float lik = obcast<kk>(a, hi);          // L[i][kk] via DPP
      const float ljk = bper(jj5 | (kk << 2), a);   // L[j][kk]
      if (i > kk && j > kk) a = fmaf(-lik, ljk, a);
    });
    const float Lm = (j <= i) ? a : 0.0f;

    // ---- strictly-lower unit factor: Lz[i][r] = L[i][r]/L_rr for r<i, else 0
    const float dv  = bper(bx_ii, dinv);   // lane (i,j): 1/L_ii (row-replicated)
    const float dvC = bper(tp, dv);        // lane (i,j): 1/L_jj (col-replicated)
    const float Lz  = (j < i) ? Lm * dvC : 0.0f;

    // prefetch Lz[i][r]: immediate swizzles (and=0x18 keeps i-bits, or=r)
    float lir[8];
    sfor<8>([&](auto RR) {
      constexpr int r = RR.value;
      lir[r] = swz<(r << 5) | 0x18>(Lz);
    });

    // ---- Y = L^{-1} X: unit forward solve (unpredicated), row scale ----
    float y = Xc;
    sfor<8>([&](auto RR) {
      constexpr int r = RR.value;
      const float yr = bper((r << 5) | j2, y);      // serial chain
      y = fmaf(-lir[r], yr, y);                     // lir==0 for i<=r
    });
    y *= dv;

    // ---- Z = L^{-1} Y^T: unit forward solve (unpredicated), row scale ----
    float z = bper(tp, y);
    sfor<8>([&](auto RR) {
      constexpr int r = RR.value;
      const float zr = bper((r << 5) | j2, z);
      z = fmaf(-lir[r], zr, z);
    });
    z *= dv;

    // ---- replicated diag D; trace via xor-tree on D (invariant) ----
    float D = bper(bx_ii, z);               // Z[i][i], replicated along row
    float t8 = D + dpp_ror8(D);             // + i^1
    t8 += swz<0x401F>(t8);                  // + i^2
    const float trz = t8 + bper(bx_self ^ 128, t8);  // + i^4
    const float s2 = 1.0e-6f * trz * trz;

    // ---- XOR-paired Jacobi (transpose trick), W = (L*prodJ)^T ----
    float W = bper(tp, Lm);
    auto jacobi_sweep = [&]() {
      sfor<7>([&](auto RR) {
        constexpr int r   = RR.value + 1;
        constexpr int xc  = r << 2;         // col-field xor on byte addr
        constexpr int xr  = r << 5;         // row-field xor on byte addr
        constexpr int msb = (r >= 4) ? 4 : ((r >= 2) ? 2 : 1);  // pair order bit
        float zr, Dq, Wr;
        if constexpr (r == 1) {
          zr = dpp_ror8(z);                 // lane^8 via DPP (VALU, no DS)
          Dq = dpp_ror8(D);
          Wr = dpp_ror8(W);
        } else if constexpr (r < 4) {
          constexpr int P = ((r << 3) << 10) | 0x1F;  // lane ^ (r<<3), in-half
          zr = swz<P>(z);
          Dq = swz<P>(D);
          Wr = swz<P>(W);
        } else {
          zr = bper(bx_self ^ xr, z);
          Dq = bper(bx_self ^ xr, D);
          Wr = bper(bx_self ^ xr, W);
        }
        const float aR = bper(bx_ii ^ xc, z);     // Z[i][i^r]
        // rotation for pair {i, i^r}; epsilon-bias makes the sign split
        // antisymmetric even at dd==0 exactly (1e-35 absorbed otherwise)
        const float dd = (D - Dq) + (((i & msb) != 0) ? -1e-35f : 1e-35f);
        const float q2 = aR + aR;
        const float h2 = fmaf(dd, dd, q2 * q2);
        const float rh = rsqf_(fmaxf(h2, 1e-38f));
        const float c2 = fmaf(0.5f * fabsf(dd), rh, 0.5f);
        const float rc = rsqf_(c2);
        const bool ok  = h2 > 1e-38f;
        const float cc = ok ? c2 * rc : 1.0f;
        const float tt = aR * (rh * rc);
        float sR = (dd < 0.0f) ? -tt : tt;
        sR = ok ? sR : 0.0f;
        // row op: G = J^T Z ; W' = J^T W ; local diag update (exact)
        const float G = fmaf(sR, zr, cc * z);
        W = fmaf(sR, Wr, cc * W);
        D = fmaf(cc, fmaf(cc, D, sR * aR), sR * fmaf(cc, aR, sR * Dq));
        // second level: z' = J^T G^T (two independent fetches from G)
        const float T  = bper(tp, G);        // G[j][i]
        const float T2 = bper(tp ^ xc, G);   // G[j][i^r]
        z = fmaf(sR, T2, cc * T);
      });
    };
    jacobi_sweep();
    jacobi_sweep();
    {
      const bool off = (i < j) && (z * z > s2);
      if (__ballot(off) != 0ull) jacobi_sweep();
    }

    // ---- eigenweights from D (all lanes, row-indexed): ev_i^tk ----
    const float wdl = __builtin_amdgcn_exp2f(tk * __builtin_amdgcn_logf(fmaxf(D, 1e-10f)));
    const float Ws  = W * wdl;   // Ws[k][j] = W[k][j] * ev_k^tk (local mul)

    // ---- Mn[i][j] = sum_k W[k][i] * Ws[k][j] ----
    float mn = 0.0f;
    sfor<8>([&](auto KK) {
      constexpr int kk = KK.value;
      const float a1 = bper((kk << 5) | i2, W);    // W[kk][i] = U[i][kk]
      const float a2 = bper((kk << 5) | j2, Ws);   // U[j][kk]*ev_kk^tk
      mn = fmaf(a1, a2, mn);
    });
    M = mn;
    Xc = Xn;
  }

  out[(size_t)((b * 16 + o) * 81 + r81) * 64 + lane] = M;
}

extern "C" void kernel_launch(void* const* d_in, const int* in_sizes, int n_in,
                              void* d_out, int out_size, void* d_ws, size_t ws_size,
                              hipStream_t stream) {
  const float* x  = (const float*)d_in[0];
  const float* wm = (const float*)d_in[1];
  float* out = (float*)d_out;
  // 5184 chains, 2 waves per 128-thr block -> 2592 blocks
  spd_fm_kernel<<<2592, 128, 0, stream>>>(x, wm, out);
}